// Round 6
// baseline (131.378 us; speedup 1.0000x reference)
//
#include <hip/hip_runtime.h>
#include <hip/hip_bf16.h>

// Problem constants
#define NF 40   // fields f
#define NI 40   // in_sub i
#define NN 40   // out_sub n
#define ED 64   // embed D, d
#define NB 256  // batch b

typedef __attribute__((ext_vector_type(8))) short   short8;
typedef __attribute__((ext_vector_type(8))) __bf16  bf16x8;
typedef __attribute__((ext_vector_type(4))) float   f32x4;

__device__ __forceinline__ unsigned short f2bf(float x) {
    union { float f; unsigned u; } v; v.f = x;
    unsigned r = v.u + 0x7FFFu + ((v.u >> 16) & 1u);   // RNE
    return (unsigned short)(r >> 16);
}

__device__ __forceinline__ bf16x8 ld_frag(const unsigned short* p) {
    return __builtin_bit_cast(bf16x8, *(const short8*)p);
}

__device__ __forceinline__ f32x4 mfma16(bf16x8 a, bf16x8 b, f32x4 c) {
    return __builtin_amdgcn_mfma_f32_16x16x32_bf16(a, b, c, 0, 0, 0);
}

// ==========================================================================
// FAST PATH (tier 2): ws holds only the n-params (bf16, fragment-ready):
//   whp[n][D(64)][d(64)] = W[n][D][d]*h[n][d]
//   alp[n][i(48)][f(64)] = alpha[f][i][n]   (pads i>=40 / f>=40 -> 0)
// Per-b data is staged in-block (LDS) by the main kernel.
//
// ROUND 6 NOTE: gif_main4 is launched THREE times (idempotent: identical
// writes each time) purely to measure its true duration via
// dur6 - dur5 = 2*(main4 + graph-node gap), since rocprof's top-5 cutoff
// (41 us harness fills) hides it. Kernel bodies are byte-identical to R5.
// ==========================================================================
#define WHP_N (64 * 64)   // 4096
#define ALP_N (48 * 64)   // 3072

// Prep: 80 blocks x 256 thr.
//   x <  40 : n = x   : whp (coalesced) + zero alp[n]'s pad region
//   x >= 40 : f = x-40: alpha slice, coalesced read, scatter write
__global__ __launch_bounds__(256) void gif_prep4(
        const float* __restrict__ W, const float* __restrict__ alpha,
        const float* __restrict__ h,
        unsigned short* __restrict__ whp, unsigned short* __restrict__ alp) {
    const int x = blockIdx.x;
    const int t = threadIdx.x;
    if (x < NN) {
        const int n = x;
        for (int idx = t; idx < 64 * 64; idx += 256) {       // whp coalesced
            int d = idx & 63;
            whp[n * WHP_N + idx] = f2bf(W[n * ED * ED + idx] * h[n * ED + d]);
        }
        for (int idx = t; idx < 8 * 64; idx += 256)          // rows i 40..47
            alp[n * ALP_N + (40 + (idx >> 6)) * 64 + (idx & 63)] = 0;
        for (int idx = t; idx < 40 * 24; idx += 256) {       // cols f 40..63
            int i = idx / 24, f = 40 + idx - i * 24;
            alp[n * ALP_N + i * 64 + f] = 0;
        }
    } else {
        const int f = x - NN;
        for (int idx = t; idx < NI * NN; idx += 256) {       // coalesced read
            int i = idx / NN, n = idx - i * NN;
            alp[n * ALP_N + i * 64 + f] = f2bf(alpha[(f * NI + i) * NN + n]);
        }
    }
}

// Main: 512 blocks x 256 thr (4 waves), 2 blocks/CU. (identical to R5)
#define PSM 72
__global__ __launch_bounds__(256, 2) void gif_main4(
        const float* __restrict__ B0, const float* __restrict__ Bi,
        const unsigned short* __restrict__ whp,
        const unsigned short* __restrict__ alp,
        float* __restrict__ out) {
    const int q = blockIdx.x >> 8;
    const int b = blockIdx.x & 255;
    const int t = threadIdx.x;
    const int lane = t & 63, w = t >> 6;
    const int quad = lane >> 4, l15 = lane & 15, fo = quad * 8;

    __shared__ __align__(16) unsigned short sBi[48 * PSM];  // [i][d]
    __shared__ __align__(16) unsigned short sBT[64 * PSM];  // [D][f]

    // ---- issue first n's param fragment loads (L2) before staging ----
    bf16x8 alA[2][3][2], whB[2][4][2];
    {
        const int n0 = q * 20 + w;
        const unsigned short* ap = alp + n0 * ALP_N;
        const unsigned short* wp = whp + n0 * WHP_N;
#pragma unroll
        for (int m = 0; m < 3; ++m)
#pragma unroll
            for (int s = 0; s < 2; ++s)
                alA[0][m][s] = ld_frag(&ap[(m * 16 + l15) * 64 + s * 32 + fo]);
#pragma unroll
        for (int tt = 0; tt < 4; ++tt)
#pragma unroll
            for (int s = 0; s < 2; ++s)
                whB[0][tt][s] = ld_frag(&wp[(tt * 16 + l15) * 64 + s * 32 + fo]);
    }

    // ---- LDS staging (fp32 -> bf16), all global reads coalesced ----
    {
        const float* bi = Bi + b * NI * ED;
        const float* b0 = B0 + b * NF * ED;
        for (int idx = t; idx < NI * ED; idx += 256) {        // sBi real rows
            int i = idx >> 6, d = idx & 63;
            sBi[i * PSM + d] = f2bf(bi[idx]);
        }
        for (int idx = t; idx < 8 * 64; idx += 256)           // sBi pad rows
            sBi[(40 + (idx >> 6)) * PSM + (idx & 63)] = 0;
        for (int idx = t; idx < NF * ED; idx += 256) {        // sBT transpose
            int f = idx >> 6, D = idx & 63;
            sBT[D * PSM + f] = f2bf(b0[idx]);
        }
        for (int idx = t; idx < 64 * 24; idx += 256) {        // sBT pad cols
            int D = idx / 24, f = 40 + idx - D * 24;
            sBT[D * PSM + f] = 0;
        }
    }
    __syncthreads();

    // ---- per-b fragments from LDS (ds_read_b128, ~2-way = free) ----
    bf16x8 biA[3][2], b0B[4][2];
#pragma unroll
    for (int m = 0; m < 3; ++m)
#pragma unroll
        for (int s = 0; s < 2; ++s)
            biA[m][s] = ld_frag(&sBi[(m * 16 + l15) * PSM + s * 32 + fo]);
#pragma unroll
    for (int tt = 0; tt < 4; ++tt)
#pragma unroll
        for (int s = 0; s < 2; ++s)
            b0B[tt][s] = ld_frag(&sBT[(tt * 16 + l15) * PSM + s * 32 + fo]);

#pragma unroll
    for (int it = 0; it < 5; ++it) {
        const int cur = it & 1, nxt = cur ^ 1;
        const int n = q * 20 + it * 4 + w;

        if (it < 4) {   // prefetch next n's fragments (hidden by MFMA body)
            const unsigned short* ap = alp + (n + 4) * ALP_N;
            const unsigned short* wp = whp + (n + 4) * WHP_N;
#pragma unroll
            for (int m = 0; m < 3; ++m)
#pragma unroll
                for (int s = 0; s < 2; ++s)
                    alA[nxt][m][s] = ld_frag(&ap[(m * 16 + l15) * 64 + s * 32 + fo]);
#pragma unroll
            for (int tt = 0; tt < 4; ++tt)
#pragma unroll
                for (int s = 0; s < 2; ++s)
                    whB[nxt][tt][s] = ld_frag(&wp[(tt * 16 + l15) * 64 + s * 32 + fo]);
        }

        float p[4];
#pragma unroll
        for (int tt = 0; tt < 4; ++tt) {
            float acc = 0.f;
#pragma unroll
            for (int m = 0; m < 3; ++m) {
                f32x4 z = {0.f, 0.f, 0.f, 0.f};
                f32x4 T = mfma16(biA[m][0], whB[cur][tt][0], z);
                T = mfma16(biA[m][1], whB[cur][tt][1], T);
                f32x4 G = mfma16(alA[cur][m][0], b0B[tt][0], z);
                G = mfma16(alA[cur][m][1], b0B[tt][1], G);
                acc += T[0] * G[0] + T[1] * G[1] + T[2] * G[2] + T[3] * G[3];
            }
            p[tt] = acc;
        }
#pragma unroll
        for (int tt = 0; tt < 4; ++tt) {
            p[tt] += __shfl_xor(p[tt], 16, 64);
            p[tt] += __shfl_xor(p[tt], 32, 64);
        }
        float v = (quad == 0) ? p[0] : (quad == 1) ? p[1] : (quad == 2) ? p[2] : p[3];
        out[(b * NN + n) * ED + lane] = v;
    }
}

// ==========================================================================
// FALLBACK (small ws): round-2 verified kernels.
// ==========================================================================
#define PS 72
#define WH_N (ED * PS)
#define AL_N (48 * PS)

__global__ __launch_bounds__(256) void gif_prep(
        const float* __restrict__ W, const float* __restrict__ alpha,
        const float* __restrict__ h,
        unsigned short* __restrict__ whp, unsigned short* __restrict__ alp) {
    const int n = blockIdx.x;
    const int t0 = blockIdx.y * 256 + threadIdx.x;
    for (int idx = t0; idx < ED * PS; idx += 1024) {
        int D = idx / PS, c = idx - D * PS;
        float v = (c < ED) ? W[n * ED * ED + D * ED + c] * h[n * ED + c] : 0.f;
        whp[n * WH_N + idx] = f2bf(v);
    }
    for (int idx = t0; idx < 48 * PS; idx += 1024) {
        int i = idx / PS, c = idx - i * PS;
        float v = (i < NI && c < NF) ? alpha[(c * NI + i) * NN + n] : 0.f;
        alp[n * AL_N + idx] = f2bf(v);
    }
}

__device__ __forceinline__ bf16x8 mk_al_frag(const float* __restrict__ alpha,
        int n, int m, int s, int l15, int quad) {
    bf16x8 r;
    const int row = m * 16 + l15;
    const int f0 = s * 32 + quad * 8;
#pragma unroll
    for (int j = 0; j < 8; ++j) {
        const int f = f0 + j;
        float v = (row < NI && f < NF) ? alpha[(f * NI + row) * NN + n] : 0.f;
        r[j] = (__bf16)v;
    }
    return r;
}
__device__ __forceinline__ bf16x8 mk_wh_frag(const float* __restrict__ W,
        const float* __restrict__ h, int n, int tt, int s, int l15, int quad) {
    bf16x8 r;
    const int row = tt * 16 + l15;
    const int k0 = s * 32 + quad * 8;
#pragma unroll
    for (int j = 0; j < 8; ++j) {
        float v = W[n * ED * ED + row * ED + k0 + j] * h[n * ED + k0 + j];
        r[j] = (__bf16)v;
    }
    return r;
}

__global__ __launch_bounds__(256) void gif_mfma(
        const float* __restrict__ B0, const float* __restrict__ Bi,
        const unsigned short* __restrict__ whp, const unsigned short* __restrict__ alp,
        const float* __restrict__ W, const float* __restrict__ alpha,
        const float* __restrict__ h, int useWs, float* __restrict__ out) {
    const int q = blockIdx.x >> 8;
    const int b = blockIdx.x & 255;

    __shared__ __align__(16) unsigned short sBi[48 * PS];
    __shared__ __align__(16) unsigned short sBT[ED * PS];

    const int t = threadIdx.x;
    for (int idx = t; idx < 48 * PS; idx += 256) {
        int i = idx / PS, c = idx - i * PS;
        sBi[idx] = (i < NI && c < ED) ? f2bf(Bi[b * NI * ED + i * ED + c])
                                      : (unsigned short)0;
    }
    for (int idx = t; idx < ED * PS; idx += 256) {
        int D = idx / PS, c = idx - D * PS;
        sBT[idx] = (c < NF) ? f2bf(B0[b * NF * ED + c * ED + D])
                            : (unsigned short)0;
    }
    __syncthreads();

    const int lane = t & 63, w = t >> 6;
    const int quad = lane >> 4, l15 = lane & 15;
    const int fragoff = quad * 8;

    bf16x8 biA[3][2], b0B[4][2];
#pragma unroll
    for (int m = 0; m < 3; ++m)
#pragma unroll
        for (int s = 0; s < 2; ++s)
            biA[m][s] = ld_frag(&sBi[(m * 16 + l15) * PS + s * 32 + fragoff]);
#pragma unroll
    for (int tt = 0; tt < 4; ++tt)
#pragma unroll
        for (int s = 0; s < 2; ++s)
            b0B[tt][s] = ld_frag(&sBT[(tt * 16 + l15) * PS + s * 32 + fragoff]);

#pragma unroll
    for (int rep = 0; rep < 2; ++rep) {
        const int n = q * 8 + w + rep * 4;

        bf16x8 alA[3][2];
        if (useWs) {
#pragma unroll
            for (int m = 0; m < 3; ++m)
#pragma unroll
                for (int s = 0; s < 2; ++s)
                    alA[m][s] = ld_frag(&alp[n * AL_N + (m * 16 + l15) * PS + s * 32 + fragoff]);
        } else {
#pragma unroll
            for (int m = 0; m < 3; ++m)
#pragma unroll
                for (int s = 0; s < 2; ++s)
                    alA[m][s] = mk_al_frag(alpha, n, m, s, l15, quad);
        }

        float p[4];
#pragma unroll
        for (int tt = 0; tt < 4; ++tt) {
            bf16x8 whB[2];
            if (useWs) {
                const unsigned short* wpp = &whp[n * WH_N + (tt * 16 + l15) * PS + fragoff];
                whB[0] = ld_frag(wpp);
                whB[1] = ld_frag(wpp + 32);
            } else {
                whB[0] = mk_wh_frag(W, h, n, tt, 0, l15, quad);
                whB[1] = mk_wh_frag(W, h, n, tt, 1, l15, quad);
            }
            float acc = 0.f;
#pragma unroll
            for (int m = 0; m < 3; ++m) {
                f32x4 z = {0.f, 0.f, 0.f, 0.f};
                f32x4 T = mfma16(biA[m][0], whB[0], z);
                T = mfma16(biA[m][1], whB[1], T);
                f32x4 G = mfma16(alA[m][0], b0B[tt][0], z);
                G = mfma16(alA[m][1], b0B[tt][1], G);
                acc += T[0] * G[0] + T[1] * G[1] + T[2] * G[2] + T[3] * G[3];
            }
            p[tt] = acc;
        }
#pragma unroll
        for (int tt = 0; tt < 4; ++tt) {
            p[tt] += __shfl_xor(p[tt], 16, 64);
            p[tt] += __shfl_xor(p[tt], 32, 64);
        }
        float v = (quad == 0) ? p[0] : (quad == 1) ? p[1] : (quad == 2) ? p[2] : p[3];
        out[(b * NN + n) * ED + lane] = v;
    }
}

// ==========================================================================
extern "C" void kernel_launch(void* const* d_in, const int* in_sizes, int n_in,
                              void* d_out, int out_size, void* d_ws, size_t ws_size,
                              hipStream_t stream) {
    const float* B0    = (const float*)d_in[0];  // (256,40,64)
    const float* Bi    = (const float*)d_in[1];  // (256,40,64)
    const float* W     = (const float*)d_in[2];  // (40,64,64)
    const float* alpha = (const float*)d_in[3];  // (40,40,40)
    const float* h     = (const float*)d_in[4];  // (40,64,1)
    float* out = (float*)d_out;                  // (256,40,64)

    const size_t need2 = (size_t)(NN * WHP_N + NN * ALP_N) * sizeof(unsigned short);
    if (ws_size >= need2) {
        unsigned short* whp = (unsigned short*)d_ws;
        unsigned short* alp = whp + (size_t)NN * WHP_N;
        gif_prep4<<<NN + NF, 256, 0, stream>>>(W, alpha, h, whp, alp);
        // ATTRIBUTION EXPERIMENT: three identical (idempotent) main launches.
        // dur6 - dur5 = 2 * (main4_time + node_gap).
        gif_main4<<<2 * NB, 256, 0, stream>>>(B0, Bi, whp, alp, out);
        gif_main4<<<2 * NB, 256, 0, stream>>>(B0, Bi, whp, alp, out);
        gif_main4<<<2 * NB, 256, 0, stream>>>(B0, Bi, whp, alp, out);
        return;
    }

    const size_t need1 = (size_t)(NN * WH_N + NN * AL_N) * sizeof(unsigned short);
    const int useWs = (ws_size >= need1) ? 1 : 0;
    unsigned short* whp = (unsigned short*)d_ws;
    unsigned short* alp = whp + (size_t)NN * WH_N;
    if (useWs) {
        gif_prep<<<dim3(NN, 4), 256, 0, stream>>>(W, alpha, h, whp, alp);
    }
    gif_mfma<<<5 * NB, 256, 0, stream>>>(B0, Bi, whp, alp, W, alpha, h, useWs, out);
}

// Round 7
// 99.895 us; speedup vs baseline: 1.3152x; 1.3152x over previous
//
#include <hip/hip_runtime.h>
#include <hip/hip_bf16.h>

// Problem constants
#define NF 40   // fields f
#define NI 40   // in_sub i
#define NN 40   // out_sub n
#define ED 64   // embed D, d
#define NB 256  // batch b

typedef __attribute__((ext_vector_type(8))) short   short8;
typedef __attribute__((ext_vector_type(8))) __bf16  bf16x8;
typedef __attribute__((ext_vector_type(4))) float   f32x4;

__device__ __forceinline__ unsigned short f2bf(float x) {
    union { float f; unsigned u; } v; v.f = x;
    unsigned r = v.u + 0x7FFFu + ((v.u >> 16) & 1u);   // RNE
    return (unsigned short)(r >> 16);
}

__device__ __forceinline__ bf16x8 ld_frag(const unsigned short* p) {
    return __builtin_bit_cast(bf16x8, *(const short8*)p);
}

__device__ __forceinline__ f32x4 mfma16(bf16x8 a, bf16x8 b, f32x4 c) {
    return __builtin_amdgcn_mfma_f32_16x16x32_bf16(a, b, c, 0, 0, 0);
}

// ==========================================================================
// FAST PATH (tier 2): ws layouts (bf16, fragment-ready, zero-padded)
//   BiP[b][i(48)][d(64)] = Bi[b][i][d]            (i>=40 -> 0)
//   B0T[b][D(64)][f(64)] = B0[b][f][D]            (f>=40 -> 0)
//   whp[n][D(64)][d(64)] = W[n][D][d]*h[n][d]
//   alp[n][i(48)][f(64)] = alpha[f][i][n]         (pads -> 0)
// ==========================================================================
#define BIP_N (48 * 64)   // 3072
#define B0T_N (64 * 64)   // 4096
#define WHP_N (64 * 64)   // 4096
#define ALP_N (48 * 64)   // 3072

// Prep: 336 blocks x 256 thr:
//   x <  256        : b = x   : BiP (coalesced) + B0T (LDS fp32 transpose)
//   256 <= x < 296  : n = x-256: whp (coalesced) + zero alp[n] pads
//   296 <= x < 336  : f = x-296: alpha slice, coalesced read, scatter write
__global__ __launch_bounds__(256) void gif_prep5(
        const float* __restrict__ B0, const float* __restrict__ Bi,
        const float* __restrict__ W, const float* __restrict__ alpha,
        const float* __restrict__ h,
        unsigned short* __restrict__ BiP, unsigned short* __restrict__ B0T,
        unsigned short* __restrict__ whp, unsigned short* __restrict__ alp) {
    const int x = blockIdx.x;
    const int t = threadIdx.x;

    if (x < NB) {
        const int b = x;
        __shared__ float sB0[NF][ED + 1];
        for (int idx = t; idx < NF * ED; idx += 256) {
            int f = idx >> 6, D = idx & 63;
            sB0[f][D] = B0[b * NF * ED + idx];
        }
        __syncthreads();
        for (int idx = t; idx < 48 * 64; idx += 256) {
            int i = idx >> 6, d = idx & 63;
            BiP[b * BIP_N + idx] = (i < NI) ? f2bf(Bi[b * NI * ED + i * ED + d])
                                            : (unsigned short)0;
        }
        for (int idx = t; idx < 64 * 64; idx += 256) {
            int D = idx >> 6, f = idx & 63;
            B0T[b * B0T_N + idx] = (f < NF) ? f2bf(sB0[f][D]) : (unsigned short)0;
        }
    } else if (x < NB + NN) {
        const int n = x - NB;
        for (int idx = t; idx < 64 * 64; idx += 256) {       // whp coalesced
            int d = idx & 63;
            whp[n * WHP_N + idx] = f2bf(W[n * ED * ED + idx] * h[n * ED + d]);
        }
        for (int idx = t; idx < 8 * 64; idx += 256)          // rows i 40..47
            alp[n * ALP_N + (40 + (idx >> 6)) * 64 + (idx & 63)] = 0;
        for (int idx = t; idx < 40 * 24; idx += 256) {       // cols f 40..63
            int i = idx / 24, f = 40 + idx - i * 24;
            alp[n * ALP_N + i * 64 + f] = 0;
        }
    } else {
        const int f = x - NB - NN;
        for (int idx = t; idx < NI * NN; idx += 256) {       // coalesced read
            int i = idx / NN, n = idx - i * NN;
            alp[n * ALP_N + i * 64 + f] = f2bf(alpha[(f * NI + i) * NN + n]);
        }
    }
}

// Main: grid (32, 10) x 256 thr. Block = (b-group of 8, n-group of 4).
// Wave w owns n = ng*4+w: its 28 param fragments live in REGISTERS for the
// whole kernel (14 one-time gathers). b-loop: double-buffered LDS copy-in of
// BiP[b]/B0T[b] (pure b128 copies into PSM=72-padded rows -> balanced banks);
// prefetch of b+1 is loaded to registers before the 48-MFMA body so the
// vmcnt wait lands after compute.
#define PSM 72
#define LBI (48 * PSM)            // 3456 elems (Bi part)
#define LBUF (LBI + 64 * PSM)     // 8064 elems = 16128 B per buffer
#define NCHUNK 896                // 14336 B / 16 B

__global__ __launch_bounds__(256, 2) void gif_main5(
        const unsigned short* __restrict__ BiP,
        const unsigned short* __restrict__ B0T,
        const unsigned short* __restrict__ whp,
        const unsigned short* __restrict__ alp,
        float* __restrict__ out) {
    const int bg = blockIdx.x;    // 0..31
    const int ng = blockIdx.y;    // 0..9
    const int t = threadIdx.x;
    const int lane = t & 63, w = t >> 6;
    const int quad = lane >> 4, l15 = lane & 15, fo = quad * 8;
    const int n = ng * 4 + w;

    __shared__ __align__(16) unsigned short sBuf[2 * LBUF];  // 32256 B

    // ---- one-time: this wave's n-params into registers (14 gathers) ----
    bf16x8 alA[3][2], whB[4][2];
    {
        const unsigned short* ap = alp + n * ALP_N;
        const unsigned short* wp = whp + n * WHP_N;
#pragma unroll
        for (int m = 0; m < 3; ++m)
#pragma unroll
            for (int s = 0; s < 2; ++s)
                alA[m][s] = ld_frag(&ap[(m * 16 + l15) * 64 + s * 32 + fo]);
#pragma unroll
        for (int tt = 0; tt < 4; ++tt)
#pragma unroll
            for (int s = 0; s < 2; ++s)
                whB[tt][s] = ld_frag(&wp[(tt * 16 + l15) * 64 + s * 32 + fo]);
    }

    // chunk c (16B): c<384 -> BiP row c>>3, col (c&7)*8 ; else B0T part
    // prologue: stage b = bg*8 into buffer 0
    float4 creg[4];
    {
        const float4* sBi = (const float4*)(BiP + (size_t)(bg * 8) * BIP_N);
        const float4* sB0 = (const float4*)(B0T + (size_t)(bg * 8) * B0T_N);
#pragma unroll
        for (int k = 0; k < 4; ++k) {
            int c = t + k * 256;
            if (c < NCHUNK) creg[k] = (c < 384) ? sBi[c] : sB0[c - 384];
        }
#pragma unroll
        for (int k = 0; k < 4; ++k) {
            int c = t + k * 256;
            if (c < NCHUNK) {
                int dst = (c < 384)
                    ? ((c >> 3) * PSM + (c & 7) * 8)
                    : (LBI + (((c - 384) >> 3) * PSM + ((c - 384) & 7) * 8));
                *(float4*)&sBuf[dst] = creg[k];
            }
        }
    }
    __syncthreads();

#pragma unroll 2
    for (int j = 0; j < 8; ++j) {
        const int b = bg * 8 + j;
        const int cur = j & 1;

        if (j < 7) {   // issue prefetch loads for b+1 (consumed after compute)
            const float4* sBi = (const float4*)(BiP + (size_t)(b + 1) * BIP_N);
            const float4* sB0 = (const float4*)(B0T + (size_t)(b + 1) * B0T_N);
#pragma unroll
            for (int k = 0; k < 4; ++k) {
                int c = t + k * 256;
                if (c < NCHUNK) creg[k] = (c < 384) ? sBi[c] : sB0[c - 384];
            }
        }

        // ---- compute (b, n) from sBuf[cur] ----
        const unsigned short* sbi = sBuf + cur * LBUF;
        const unsigned short* sbt = sbi + LBI;
        bf16x8 biA[3][2];
#pragma unroll
        for (int m = 0; m < 3; ++m)
#pragma unroll
            for (int s = 0; s < 2; ++s)
                biA[m][s] = ld_frag(&sbi[(m * 16 + l15) * PSM + s * 32 + fo]);

        float p[4];
#pragma unroll
        for (int tt = 0; tt < 4; ++tt) {
            bf16x8 bb0 = ld_frag(&sbt[(tt * 16 + l15) * PSM + fo]);
            bf16x8 bb1 = ld_frag(&sbt[(tt * 16 + l15) * PSM + 32 + fo]);
            float acc = 0.f;
#pragma unroll
            for (int m = 0; m < 3; ++m) {
                f32x4 z = {0.f, 0.f, 0.f, 0.f};
                f32x4 T = mfma16(biA[m][0], whB[tt][0], z);
                T = mfma16(biA[m][1], whB[tt][1], T);
                f32x4 G = mfma16(alA[m][0], bb0, z);
                G = mfma16(alA[m][1], bb1, G);
                acc += T[0] * G[0] + T[1] * G[1] + T[2] * G[2] + T[3] * G[3];
            }
            p[tt] = acc;
        }
#pragma unroll
        for (int tt = 0; tt < 4; ++tt) {
            p[tt] += __shfl_xor(p[tt], 16, 64);
            p[tt] += __shfl_xor(p[tt], 32, 64);
        }
        float v = (quad == 0) ? p[0] : (quad == 1) ? p[1] : (quad == 2) ? p[2] : p[3];
        out[(b * NN + n) * ED + lane] = v;

        if (j < 7) {   // write prefetched b+1 into the other buffer
            const int nb = cur ^ 1;
#pragma unroll
            for (int k = 0; k < 4; ++k) {
                int c = t + k * 256;
                if (c < NCHUNK) {
                    int dst = (c < 384)
                        ? ((c >> 3) * PSM + (c & 7) * 8)
                        : (LBI + (((c - 384) >> 3) * PSM + ((c - 384) & 7) * 8));
                    *(float4*)&sBuf[nb * LBUF + dst] = creg[k];
                }
            }
        }
        __syncthreads();
    }
}

// ==========================================================================
// FALLBACK (small ws): round-2 verified kernels.
// ==========================================================================
#define PS 72
#define WH_N (ED * PS)
#define AL_N (48 * PS)

__global__ __launch_bounds__(256) void gif_prep(
        const float* __restrict__ W, const float* __restrict__ alpha,
        const float* __restrict__ h,
        unsigned short* __restrict__ whp, unsigned short* __restrict__ alp) {
    const int n = blockIdx.x;
    const int t0 = blockIdx.y * 256 + threadIdx.x;
    for (int idx = t0; idx < ED * PS; idx += 1024) {
        int D = idx / PS, c = idx - D * PS;
        float v = (c < ED) ? W[n * ED * ED + D * ED + c] * h[n * ED + c] : 0.f;
        whp[n * WH_N + idx] = f2bf(v);
    }
    for (int idx = t0; idx < 48 * PS; idx += 1024) {
        int i = idx / PS, c = idx - i * PS;
        float v = (i < NI && c < NF) ? alpha[(c * NI + i) * NN + n] : 0.f;
        alp[n * AL_N + idx] = f2bf(v);
    }
}

__device__ __forceinline__ bf16x8 mk_al_frag(const float* __restrict__ alpha,
        int n, int m, int s, int l15, int quad) {
    bf16x8 r;
    const int row = m * 16 + l15;
    const int f0 = s * 32 + quad * 8;
#pragma unroll
    for (int j = 0; j < 8; ++j) {
        const int f = f0 + j;
        float v = (row < NI && f < NF) ? alpha[(f * NI + row) * NN + n] : 0.f;
        r[j] = (__bf16)v;
    }
    return r;
}
__device__ __forceinline__ bf16x8 mk_wh_frag(const float* __restrict__ W,
        const float* __restrict__ h, int n, int tt, int s, int l15, int quad) {
    bf16x8 r;
    const int row = tt * 16 + l15;
    const int k0 = s * 32 + quad * 8;
#pragma unroll
    for (int j = 0; j < 8; ++j) {
        float v = W[n * ED * ED + row * ED + k0 + j] * h[n * ED + k0 + j];
        r[j] = (__bf16)v;
    }
    return r;
}

__global__ __launch_bounds__(256) void gif_mfma(
        const float* __restrict__ B0, const float* __restrict__ Bi,
        const unsigned short* __restrict__ whp, const unsigned short* __restrict__ alp,
        const float* __restrict__ W, const float* __restrict__ alpha,
        const float* __restrict__ h, int useWs, float* __restrict__ out) {
    const int q = blockIdx.x >> 8;
    const int b = blockIdx.x & 255;

    __shared__ __align__(16) unsigned short sBi[48 * PS];
    __shared__ __align__(16) unsigned short sBT[ED * PS];

    const int t = threadIdx.x;
    for (int idx = t; idx < 48 * PS; idx += 256) {
        int i = idx / PS, c = idx - i * PS;
        sBi[idx] = (i < NI && c < ED) ? f2bf(Bi[b * NI * ED + i * ED + c])
                                      : (unsigned short)0;
    }
    for (int idx = t; idx < ED * PS; idx += 256) {
        int D = idx / PS, c = idx - D * PS;
        sBT[idx] = (c < NF) ? f2bf(B0[b * NF * ED + c * ED + D])
                            : (unsigned short)0;
    }
    __syncthreads();

    const int lane = t & 63, w = t >> 6;
    const int quad = lane >> 4, l15 = lane & 15;
    const int fragoff = quad * 8;

    bf16x8 biA[3][2], b0B[4][2];
#pragma unroll
    for (int m = 0; m < 3; ++m)
#pragma unroll
        for (int s = 0; s < 2; ++s)
            biA[m][s] = ld_frag(&sBi[(m * 16 + l15) * PS + s * 32 + fragoff]);
#pragma unroll
    for (int tt = 0; tt < 4; ++tt)
#pragma unroll
        for (int s = 0; s < 2; ++s)
            b0B[tt][s] = ld_frag(&sBT[(tt * 16 + l15) * PS + s * 32 + fragoff]);

#pragma unroll
    for (int rep = 0; rep < 2; ++rep) {
        const int n = q * 8 + w + rep * 4;

        bf16x8 alA[3][2];
        if (useWs) {
#pragma unroll
            for (int m = 0; m < 3; ++m)
#pragma unroll
                for (int s = 0; s < 2; ++s)
                    alA[m][s] = ld_frag(&alp[n * AL_N + (m * 16 + l15) * PS + s * 32 + fragoff]);
        } else {
#pragma unroll
            for (int m = 0; m < 3; ++m)
#pragma unroll
                for (int s = 0; s < 2; ++s)
                    alA[m][s] = mk_al_frag(alpha, n, m, s, l15, quad);
        }

        float p[4];
#pragma unroll
        for (int tt = 0; tt < 4; ++tt) {
            bf16x8 whB2[2];
            if (useWs) {
                const unsigned short* wpp = &whp[n * WH_N + (tt * 16 + l15) * PS + fragoff];
                whB2[0] = ld_frag(wpp);
                whB2[1] = ld_frag(wpp + 32);
            } else {
                whB2[0] = mk_wh_frag(W, h, n, tt, 0, l15, quad);
                whB2[1] = mk_wh_frag(W, h, n, tt, 1, l15, quad);
            }
            float acc = 0.f;
#pragma unroll
            for (int m = 0; m < 3; ++m) {
                f32x4 z = {0.f, 0.f, 0.f, 0.f};
                f32x4 T = mfma16(biA[m][0], whB2[0], z);
                T = mfma16(biA[m][1], whB2[1], T);
                f32x4 G = mfma16(alA[m][0], b0B[tt][0], z);
                G = mfma16(alA[m][1], b0B[tt][1], G);
                acc += T[0] * G[0] + T[1] * G[1] + T[2] * G[2] + T[3] * G[3];
            }
            p[tt] = acc;
        }
#pragma unroll
        for (int tt = 0; tt < 4; ++tt) {
            p[tt] += __shfl_xor(p[tt], 16, 64);
            p[tt] += __shfl_xor(p[tt], 32, 64);
        }
        float v = (quad == 0) ? p[0] : (quad == 1) ? p[1] : (quad == 2) ? p[2] : p[3];
        out[(b * NN + n) * ED + lane] = v;
    }
}

// ==========================================================================
extern "C" void kernel_launch(void* const* d_in, const int* in_sizes, int n_in,
                              void* d_out, int out_size, void* d_ws, size_t ws_size,
                              hipStream_t stream) {
    const float* B0    = (const float*)d_in[0];  // (256,40,64)
    const float* Bi    = (const float*)d_in[1];  // (256,40,64)
    const float* W     = (const float*)d_in[2];  // (40,64,64)
    const float* alpha = (const float*)d_in[3];  // (40,40,40)
    const float* h     = (const float*)d_in[4];  // (40,64,1)
    float* out = (float*)d_out;                  // (256,40,64)

    const size_t need2 =
        (size_t)(NB * BIP_N + NB * B0T_N + NN * WHP_N + NN * ALP_N) * sizeof(unsigned short);
    if (ws_size >= need2) {
        unsigned short* BiP = (unsigned short*)d_ws;
        unsigned short* B0T = BiP + (size_t)NB * BIP_N;
        unsigned short* whp = B0T + (size_t)NB * B0T_N;
        unsigned short* alp = whp + (size_t)NN * WHP_N;
        gif_prep5<<<NB + NN + NF, 256, 0, stream>>>(B0, Bi, W, alpha, h, BiP, B0T, whp, alp);
        gif_main5<<<dim3(32, 10), 256, 0, stream>>>(BiP, B0T, whp, alp, out);
        return;
    }

    const size_t need1 = (size_t)(NN * WH_N + NN * AL_N) * sizeof(unsigned short);
    const int useWs = (ws_size >= need1) ? 1 : 0;
    unsigned short* whp = (unsigned short*)d_ws;
    unsigned short* alp = whp + (size_t)NN * WH_N;
    if (useWs) {
        gif_prep<<<dim3(NN, 4), 256, 0, stream>>>(W, alpha, h, whp, alp);
    }
    gif_mfma<<<5 * NB, 256, 0, stream>>>(B0, Bi, whp, alp, W, alpha, h, useWs, out);
}

// Round 8
// 97.126 us; speedup vs baseline: 1.3526x; 1.0285x over previous
//
#include <hip/hip_runtime.h>
#include <hip/hip_bf16.h>

// Problem constants
#define NF 40   // fields f
#define NI 40   // in_sub i
#define NN 40   // out_sub n
#define ED 64   // embed D, d
#define NB 256  // batch b

typedef __attribute__((ext_vector_type(8))) short   short8;
typedef __attribute__((ext_vector_type(8))) __bf16  bf16x8;
typedef __attribute__((ext_vector_type(4))) float   f32x4;

__device__ __forceinline__ unsigned short f2bf(float x) {
    union { float f; unsigned u; } v; v.f = x;
    unsigned r = v.u + 0x7FFFu + ((v.u >> 16) & 1u);   // RNE
    return (unsigned short)(r >> 16);
}

__device__ __forceinline__ bf16x8 ld_frag(const unsigned short* p) {
    return __builtin_bit_cast(bf16x8, *(const short8*)p);
}

__device__ __forceinline__ f32x4 mfma16(bf16x8 a, bf16x8 b, f32x4 c) {
    return __builtin_amdgcn_mfma_f32_16x16x32_bf16(a, b, c, 0, 0, 0);
}

// ==========================================================================
// SINGLE fused kernel. Grid (64, 10) x 256 thr (4 waves), no workspace.
//   block = (bg: 4 b's, ng: 4 n's); wave w owns n = ng*4 + w.
//   Prologue (once): wave builds Wh B-frags in registers straight from W,h
//   (coalesced float4, byte-perfect coverage of W[n]); block stages
//   alpha[f][i][n0..n0+4) via aligned float4 reads into 4 LDS planes
//   (PSM=72 padded), wave reads its alA frags once.
//   b-loop (4 iters): R5-proven in-block fp32->bf16 LDS staging of
//   Bi[b] / B0[b]^T, 48 MFMAs, shuffle-reduce, store.
// LDS: 27648 (sAl) + 6912 (sBi) + 9216 (sBT) = 43776 B -> 3 blocks/CU.
// ==========================================================================
#define PSM 72
#define AL_PLANE (48 * PSM)   // 3456 elems per n-plane
#define LBI (48 * PSM)        // 3456
#define LBT (64 * PSM)        // 4608

__global__ __launch_bounds__(256, 3) void gif_fused(
        const float* __restrict__ B0, const float* __restrict__ Bi,
        const float* __restrict__ W, const float* __restrict__ alpha,
        const float* __restrict__ h, float* __restrict__ out) {
    const int bg = blockIdx.x;         // 0..63 : b in [bg*4, bg*4+4)
    const int ng = blockIdx.y;         // 0..9  : n in [ng*4, ng*4+4)
    const int t = threadIdx.x;
    const int lane = t & 63, w = t >> 6;
    const int quad = lane >> 4, l15 = lane & 15, fo = quad * 8;
    const int n = ng * 4 + w;
    const int n0 = ng * 4;

    __shared__ __align__(16) unsigned short sAl[4 * AL_PLANE]; // 27648 B
    __shared__ __align__(16) unsigned short sBi[LBI];          //  6912 B
    __shared__ __align__(16) unsigned short sBT[LBT];          //  9216 B

    // ---- zero alpha planes (pads must be 0) ----
    for (int idx = t; idx < 4 * AL_PLANE / 2; idx += 256)
        ((unsigned int*)sAl)[idx] = 0;
    __syncthreads();

    // ---- alpha -> 4 LDS planes: plane nn holds al[n0+nn][i][f] ----
    // aligned float4 read covers the block's 4 n's per (f,i) line.
    for (int idx = t; idx < NF * NI; idx += 256) {
        int f = idx / NI, i = idx - f * NI;
        float4 a4 = *(const float4*)&alpha[(size_t)(f * NI + i) * NN + n0];
        sAl[0 * AL_PLANE + i * PSM + f] = f2bf(a4.x);
        sAl[1 * AL_PLANE + i * PSM + f] = f2bf(a4.y);
        sAl[2 * AL_PLANE + i * PSM + f] = f2bf(a4.z);
        sAl[3 * AL_PLANE + i * PSM + f] = f2bf(a4.w);
    }

    // ---- Wh B-fragments built directly in registers from W, h ----
    bf16x8 whB[4][2];
    {
        const float* hb = h + n * ED;
        float4 ha[2][2];
        ha[0][0] = *(const float4*)&hb[fo];
        ha[0][1] = *(const float4*)&hb[fo + 4];
        ha[1][0] = *(const float4*)&hb[32 + fo];
        ha[1][1] = *(const float4*)&hb[32 + fo + 4];
        const float* wbase = W + (size_t)n * ED * ED;
#pragma unroll
        for (int tt = 0; tt < 4; ++tt) {
#pragma unroll
            for (int s = 0; s < 2; ++s) {
                const float* wr = wbase + (tt * 16 + l15) * ED + s * 32 + fo;
                float4 wa = *(const float4*)wr;
                float4 wv = *(const float4*)(wr + 4);
                union { unsigned short u[8]; bf16x8 v; } r;
                r.u[0] = f2bf(wa.x * ha[s][0].x);
                r.u[1] = f2bf(wa.y * ha[s][0].y);
                r.u[2] = f2bf(wa.z * ha[s][0].z);
                r.u[3] = f2bf(wa.w * ha[s][0].w);
                r.u[4] = f2bf(wv.x * ha[s][1].x);
                r.u[5] = f2bf(wv.y * ha[s][1].y);
                r.u[6] = f2bf(wv.z * ha[s][1].z);
                r.u[7] = f2bf(wv.w * ha[s][1].w);
                whB[tt][s] = r.v;
            }
        }
    }
    __syncthreads();

    // ---- alA A-fragments from this wave's plane (read once) ----
    bf16x8 alA[3][2];
    {
        const unsigned short* ap = sAl + w * AL_PLANE;
#pragma unroll
        for (int m = 0; m < 3; ++m)
#pragma unroll
            for (int s = 0; s < 2; ++s)
                alA[m][s] = ld_frag(&ap[(m * 16 + l15) * PSM + s * 32 + fo]);
    }

    // ---- b-loop ----
    for (int j = 0; j < 4; ++j) {
        const int b = bg * 4 + j;
        if (j) __syncthreads();   // previous iteration's compute done

        // stage Bi[b] and B0[b]^T into LDS (coalesced global reads)
        const float* bi = Bi + (size_t)b * NI * ED;
        const float* b0 = B0 + (size_t)b * NF * ED;
        for (int idx = t; idx < NI * ED; idx += 256) {
            int i = idx >> 6, d = idx & 63;
            sBi[i * PSM + d] = f2bf(bi[idx]);
        }
        for (int idx = t; idx < 8 * 64; idx += 256)          // pad rows i 40..47
            sBi[(40 + (idx >> 6)) * PSM + (idx & 63)] = 0;
        for (int idx = t; idx < NF * ED; idx += 256) {       // transpose write
            int f = idx >> 6, D = idx & 63;
            sBT[D * PSM + f] = f2bf(b0[idx]);
        }
        for (int idx = t; idx < 64 * 24; idx += 256) {       // pad cols f 40..63
            int D = idx / 24, f = 40 + idx - D * 24;
            sBT[D * PSM + f] = 0;
        }
        __syncthreads();

        bf16x8 biA[3][2];
#pragma unroll
        for (int m = 0; m < 3; ++m)
#pragma unroll
            for (int s = 0; s < 2; ++s)
                biA[m][s] = ld_frag(&sBi[(m * 16 + l15) * PSM + s * 32 + fo]);

        float p[4];
#pragma unroll
        for (int tt = 0; tt < 4; ++tt) {
            bf16x8 bb0 = ld_frag(&sBT[(tt * 16 + l15) * PSM + fo]);
            bf16x8 bb1 = ld_frag(&sBT[(tt * 16 + l15) * PSM + 32 + fo]);
            float acc = 0.f;
#pragma unroll
            for (int m = 0; m < 3; ++m) {
                f32x4 z = {0.f, 0.f, 0.f, 0.f};
                f32x4 T = mfma16(biA[m][0], whB[tt][0], z);
                T = mfma16(biA[m][1], whB[tt][1], T);
                f32x4 G = mfma16(alA[m][0], bb0, z);
                G = mfma16(alA[m][1], bb1, G);
                acc += T[0] * G[0] + T[1] * G[1] + T[2] * G[2] + T[3] * G[3];
            }
            p[tt] = acc;
        }
#pragma unroll
        for (int tt = 0; tt < 4; ++tt) {
            p[tt] += __shfl_xor(p[tt], 16, 64);
            p[tt] += __shfl_xor(p[tt], 32, 64);
        }
        float v = (quad == 0) ? p[0] : (quad == 1) ? p[1] : (quad == 2) ? p[2] : p[3];
        out[((size_t)b * NN + n) * ED + lane] = v;
    }
}

// ==========================================================================
extern "C" void kernel_launch(void* const* d_in, const int* in_sizes, int n_in,
                              void* d_out, int out_size, void* d_ws, size_t ws_size,
                              hipStream_t stream) {
    const float* B0    = (const float*)d_in[0];  // (256,40,64)
    const float* Bi    = (const float*)d_in[1];  // (256,40,64)
    const float* W     = (const float*)d_in[2];  // (40,64,64)
    const float* alpha = (const float*)d_in[3];  // (40,40,40)
    const float* h     = (const float*)d_in[4];  // (40,64,1)
    float* out = (float*)d_out;                  // (256,40,64)

    // Single launch, no workspace needed.
    gif_fused<<<dim3(NB / 4, NN / 4), 256, 0, stream>>>(B0, Bi, W, alpha, h, out);
}